// Round 5
// baseline (1042.638 us; speedup 1.0000x reference)
//
#include <hip/hip_runtime.h>
#include <cstdint>
#include <cstddef>

typedef unsigned short u16;
typedef __bf16 bf16x8 __attribute__((ext_vector_type(8)));
typedef float f32x4 __attribute__((ext_vector_type(4)));

#define GLOBAL_AS __attribute__((address_space(1)))
#define LDS_AS    __attribute__((address_space(3)))

__device__ __forceinline__ float bf2f(u16 v) {
  return __builtin_bit_cast(float, (uint32_t)v << 16);
}
__device__ __forceinline__ u16 f2bf(float f) {
  uint32_t u = __builtin_bit_cast(uint32_t, f);
  u += 0x7FFFu + ((u >> 16) & 1u);
  return (u16)(u >> 16);
}
// external (input) scalar load: dtype decided by runtime flag
__device__ __forceinline__ float extload(const void* p, size_t i, int isf) {
  return isf ? ((const float*)p)[i] : bf2f(((const u16*)p)[i]);
}
__device__ __forceinline__ void gl_lds16(const void* g, void* l) {
  __builtin_amdgcn_global_load_lds((const GLOBAL_AS void*)g, (LDS_AS void*)l, 16, 0, 0);
}

// ---------------------------------------------------------------------------
// dtype sniff: bf16 data has exponents <= ~0x81; fp32-misread-as-u16 has
// ~44% of words with exponent >= 0x90. flag=1 -> external dtype fp32.
// ---------------------------------------------------------------------------
__global__ __launch_bounds__(256) void sniff_k(const u16* __restrict__ x, int* __restrict__ flag) {
  const int t = threadIdx.x;
  int cnt = 0;
#pragma unroll
  for (int j = 0; j < 16; ++j) {
    const u16 w = x[t * 16 + j];
    const int e = (w >> 7) & 0xFF;
    cnt += (e >= 0x90) ? 1 : 0;
  }
#pragma unroll
  for (int o = 32; o; o >>= 1) cnt += __shfl_xor(cnt, o);
  __shared__ int red[4];
  if ((t & 63) == 0) red[t >> 6] = cnt;
  __syncthreads();
  if (t == 0) flag[0] = (red[0] + red[1] + red[2] + red[3] > 16) ? 1 : 0;
}

// canonicalize weight matrix to bf16 (copy if already bf16)
__global__ __launch_bounds__(256) void cvt_k(const void* __restrict__ in, u16* __restrict__ out,
                                             const int* __restrict__ flagp, int n) {
  const int i = (blockIdx.x * 256 + threadIdx.x) * 4;
  if (i >= n) return;
  if (*flagp) {
    const float4 v = *(const float4*)((const float*)in + i);
    out[i] = f2bf(v.x); out[i + 1] = f2bf(v.y); out[i + 2] = f2bf(v.z); out[i + 3] = f2bf(v.w);
  } else {
    *(ushort4*)(out + i) = *(const ushort4*)((const u16*)in + i);
  }
}

// ---------------------------------------------------------------------------
// LayerNorm row of 1024. INTF32: input is internal fp32 ws; else external (flag).
// ---------------------------------------------------------------------------
template<bool INTF32>
__global__ __launch_bounds__(256) void ln_k(const void* __restrict__ inp,
                                            const void* __restrict__ w,
                                            const void* __restrict__ b,
                                            u16* __restrict__ out,
                                            const int* __restrict__ flagp)
{
  const int isf = *flagp;
  const int row = blockIdx.x;
  const int t = threadIdx.x;
  float x0, x1, x2, x3;
  if (INTF32 || isf) {
    const float4 vv = ((const float4*)((const float*)inp + (size_t)row * 1024))[t];
    x0 = vv.x; x1 = vv.y; x2 = vv.z; x3 = vv.w;
  } else {
    const ushort4 vv = ((const ushort4*)((const u16*)inp + (size_t)row * 1024))[t];
    x0 = bf2f(vv.x); x1 = bf2f(vv.y); x2 = bf2f(vv.z); x3 = bf2f(vv.w);
  }
  float s = x0 + x1 + x2 + x3;
  float sq = x0 * x0 + x1 * x1 + x2 * x2 + x3 * x3;
#pragma unroll
  for (int o = 32; o; o >>= 1) { s += __shfl_xor(s, o); sq += __shfl_xor(sq, o); }
  __shared__ float red[8];
  const int wv = t >> 6;
  if ((t & 63) == 0) { red[wv] = s; red[wv + 4] = sq; }
  __syncthreads();
  s = red[0] + red[1] + red[2] + red[3];
  sq = red[4] + red[5] + red[6] + red[7];
  const float mu = s * (1.0f / 1024.0f);
  const float var = sq * (1.0f / 1024.0f) - mu * mu;
  const float rstd = rsqrtf(var + 1e-5f);
  const int c0 = t * 4;
  u16* o4 = out + (size_t)row * 1024 + c0;
  o4[0] = f2bf((x0 - mu) * rstd * extload(w, c0 + 0, isf) + extload(b, c0 + 0, isf));
  o4[1] = f2bf((x1 - mu) * rstd * extload(w, c0 + 1, isf) + extload(b, c0 + 1, isf));
  o4[2] = f2bf((x2 - mu) * rstd * extload(w, c0 + 2, isf) + extload(b, c0 + 2, isf));
  o4[3] = f2bf((x3 - mu) * rstd * extload(w, c0 + 3, isf) + extload(b, c0 + 3, isf));
}

// ---------------------------------------------------------------------------
// bf16 GEMM: out[m,n] = sum_k A[m,k]*B[n,k]  (both K-contiguous, internal bf16).
// EPI 0: out bf16 = acc + bias
// EPI 1: out fp32 = acc + bias + ext(auxb)            (residual to fp32 ws)
// EPI 2: out bf16 = relu(acc + bias) * (ext(auxb)>0.5)
// EPI 3: out EXT  = intf32(auxf) + (acc + bias) * (ext(auxb)>0.5)
// ---------------------------------------------------------------------------
template<int EPI>
__global__ __launch_bounds__(256, 2) void gemm_bt(
    const u16* __restrict__ A, const u16* __restrict__ B,
    const void* __restrict__ bias, const void* __restrict__ auxb,
    const float* __restrict__ auxf, void* __restrict__ outp,
    int M, int N, int K, const int* __restrict__ flagp)
{
  __shared__ u16 sA[128 * 32];
  __shared__ u16 sB[128 * 32];
  const int t = threadIdx.x;
  const int lane = t & 63;
  const int wv = t >> 6;
  const int wm = (wv >> 1) << 6;
  const int wn = (wv & 1) << 6;
  const int bm = blockIdx.y << 7;
  const int bn = blockIdx.x << 7;

  f32x4 acc[4][4] = {};

  const int ldr = t >> 2;     // staging row 0..63 (+64 for i=1)
  const int lseg = t & 3;     // physical 16B segment slot
  const int fr = lane & 15;
  const int q = lane >> 4;

  for (int kt = 0; kt < K; kt += 32) {
    __syncthreads();
#pragma unroll
    for (int i = 0; i < 2; ++i) {
      const int r = ldr + (i << 6);
      const int sl = lseg ^ ((r >> 1) & 3);   // XOR seg swizzle
      gl_lds16(A + (size_t)(bm + r) * K + kt + (sl << 3), &sA[(((i << 8) + t) << 3)]);
      gl_lds16(B + (size_t)(bn + r) * K + kt + (sl << 3), &sB[(((i << 8) + t) << 3)]);
    }
    asm volatile("s_waitcnt vmcnt(0)" ::: "memory");
    __syncthreads();

    bf16x8 af[4], bfv[4];
#pragma unroll
    for (int i = 0; i < 4; ++i) {
      const int rr = wm + (i << 4) + fr;
      af[i] = *(const bf16x8*)&sA[(rr << 5) + ((q ^ ((rr >> 1) & 3)) << 3)];
      const int nn = wn + (i << 4) + fr;
      bfv[i] = *(const bf16x8*)&sB[(nn << 5) + ((q ^ ((nn >> 1) & 3)) << 3)];
    }
#pragma unroll
    for (int mi = 0; mi < 4; ++mi)
#pragma unroll
      for (int ni = 0; ni < 4; ++ni)
        acc[mi][ni] = __builtin_amdgcn_mfma_f32_16x16x32_bf16(af[mi], bfv[ni], acc[mi][ni], 0, 0, 0);
  }

  const int isf = *flagp;
#pragma unroll
  for (int mi = 0; mi < 4; ++mi) {
#pragma unroll
    for (int ni = 0; ni < 4; ++ni) {
#pragma unroll
      for (int r = 0; r < 4; ++r) {
        const int gm = bm + wm + (mi << 4) + (q << 2) + r;
        const int gn = bn + wn + (ni << 4) + fr;
        const size_t idx = (size_t)gm * N + gn;
        float v = acc[mi][ni][r] + extload(bias, gn, isf);
        if (EPI == 0) {
          ((u16*)outp)[idx] = f2bf(v);
        } else if (EPI == 1) {
          ((float*)outp)[idx] = v + extload(auxb, idx, isf);
        } else if (EPI == 2) {
          const float keep = extload(auxb, idx, isf) > 0.5f ? 1.0f : 0.0f;
          ((u16*)outp)[idx] = f2bf(fmaxf(v, 0.0f) * keep);
        } else {
          const float keep = extload(auxb, idx, isf) > 0.5f ? 1.0f : 0.0f;
          const float o = auxf[idx] + v * keep;
          if (isf) ((float*)outp)[idx] = o;
          else     ((u16*)outp)[idx] = f2bf(o);
        }
      }
    }
  }
}

// ---------------------------------------------------------------------------
// V transpose: vt[b][h][d][n] = qkv[b*1024+n][2048 + h*64 + d]  (bf16)
// block = one (b,h,ntile of 64 keys); 64x64 tile via LDS.
// ---------------------------------------------------------------------------
__global__ __launch_bounds__(256) void vtrans_k(const u16* __restrict__ qkv,
                                                u16* __restrict__ vt)
{
  __shared__ u16 tile[64][72];
  const int blk = blockIdx.x;
  const int nt = blk & 15, h = (blk >> 4) & 15, b = blk >> 8;
  const int t = threadIdx.x;
#pragma unroll
  for (int it = 0; it < 2; ++it) {
    const int li = it * 256 + t, r = li >> 3, sg = li & 7;
    const uint4 g = *(const uint4*)(qkv + ((size_t)b * 1024 + nt * 64 + r) * 3072 + 2048 + h * 64 + sg * 8);
    *(uint4*)&tile[r][sg * 8] = g;
  }
  __syncthreads();
#pragma unroll
  for (int it = 0; it < 2; ++it) {
    const int li = it * 256 + t, d = li >> 3, sg = li & 7;
    u16 tmp[8];
#pragma unroll
    for (int j = 0; j < 8; ++j) tmp[j] = tile[sg * 8 + j][d];
    *(uint4*)(vt + (((size_t)(b * 16 + h)) * 64 + d) * 1024 + nt * 64 + sg * 8) = *(const uint4*)tmp;
  }
}

// ---------------------------------------------------------------------------
// Fused sparse attention v4 (resubmit; r4 was an infra core-dump, not a
// kernel verdict): v3b selection pipeline (mu/sigma bracket, dual-threshold
// search, fused keep+exp, one-barrier es+P write, deferred 1/es at the
// output) WITHOUT the V-register-prefetch: r3 counters showed it pushed peak
// VGPR pressure past budget -> 140 MB scratch spill (WRITE_SIZE 16->157 MB)
// that ate the win. Phase D loads V^T straight from global (L2-resident),
// as in the proven 323 us version.
// ---------------------------------------------------------------------------
__global__ __launch_bounds__(256, 4) void attn_k(const u16* __restrict__ qkv,
                                                 const u16* __restrict__ vt,
                                                 u16* __restrict__ aout)
{
  __shared__ u16 sP[16 * 1032];          // unnormalized P bf16 [query][key]
  __shared__ float2 red2[4][16];         // per-wave stats {sum, sumsq}
  __shared__ uint cntb[2][4][16];        // packed dual counts (double-buffered)
  __shared__ uint fcnt[4][16];           // fallback packed {>=thr, band} counts
  __shared__ float esred[4][16];         // exp-sum partials

  const int t = threadIdx.x;
  const int lane = t & 63;
  const int wv = t >> 6;
  const int bid = blockIdx.x;
  const int sw = ((bid & 7) << 10) | (bid >> 3);   // bijective XCD swizzle (8192 = 8*1024)
  const int bh = sw >> 6;
  const int rb = sw & 63;
  const int b = bh >> 4, h = bh & 15;
  const size_t row0 = (size_t)b * 1024;
  const int colQ = h * 64;
  const int fr = lane & 15, q = lane >> 4;

  // Q fragments (B operand of swapped mfma): rows fr = query
  const u16* qrow = qkv + (row0 + rb * 16 + fr) * 3072 + colQ + q * 8;
  const bf16x8 bq0 = *(const bf16x8*)(qrow);
  const bf16x8 bq1 = *(const bf16x8*)(qrow + 32);

  // ---- phase B: swapped scores. Wave wv owns keys [wv*256, wv*256+256).
  // v2[tt][r] = score[key = wv*256 + tt*16 + q*4 + r][query = fr]
  float v2[16][4];
  const u16* kbase = qkv + (row0 + wv * 256 + fr) * 3072 + 1024 + colQ + q * 8;
#pragma unroll
  for (int tt = 0; tt < 16; ++tt) {
    const u16* kp = kbase + (size_t)tt * 16 * 3072;
    const bf16x8 ak0 = *(const bf16x8*)(kp);
    const bf16x8 ak1 = *(const bf16x8*)(kp + 32);
    f32x4 sacc = {};
    sacc = __builtin_amdgcn_mfma_f32_16x16x32_bf16(ak0, bq0, sacc, 0, 0, 0);
    sacc = __builtin_amdgcn_mfma_f32_16x16x32_bf16(ak1, bq1, sacc, 0, 0, 0);
#pragma unroll
    for (int r = 0; r < 4; ++r) v2[tt][r] = sacc[r];
  }

  // ---- stats: sum & sumsq only (bracket + exp-center come from mu, sigma)
  float sm = 0.f, sq = 0.f;
#pragma unroll
  for (int tt = 0; tt < 16; ++tt)
#pragma unroll
    for (int r = 0; r < 4; ++r) {
      const float x = v2[tt][r];
      sm += x; sq += x * x;
    }
  sm += __shfl_xor(sm, 16); sm += __shfl_xor(sm, 32);
  sq += __shfl_xor(sq, 16); sq += __shfl_xor(sq, 32);
  if (lane < 16) red2[wv][fr] = make_float2(sm, sq);
  __syncthreads();
  {
    const float2 a0 = red2[0][fr], a1 = red2[1][fr], a2 = red2[2][fr], a3 = red2[3][fr];
    sm = a0.x + a1.x + a2.x + a3.x;
    sq = a0.y + a1.y + a2.y + a3.y;
  }

  // ---- top-102 threshold search: bracket mu +/- 6 sigma, dual points/iter
  const float mu = sm * (1.0f / 1024.0f);
  const float var = fmaxf(sq * (1.0f / 1024.0f) - mu * mu, 0.0f);
  const float sd = sqrtf(var + 1e-20f);
  float lo = mu - 6.0f * sd;
  float hi = mu + 6.0f * sd;
  const float M = hi;                    // exp center (>= max w.h.p.; harmless if not)
  int nlo = 1024, nhi = 0;
  bool done = false;
  float texact = 0.f;
  float t1 = mu + 1.10f * sd;            // ~13.6% quantile (count ~139)
  float t2 = mu + 1.50f * sd;            // ~6.7% quantile (count ~68)

  for (int it = 0; it < 6; ++it) {
    if (__ballot(!done) == 0ull) break;            // identical across waves
    int c1 = 0, c2 = 0;
#pragma unroll
    for (int tt = 0; tt < 16; ++tt)
#pragma unroll
      for (int r = 0; r < 4; ++r) {
        const float x = v2[tt][r];
        c1 += (x >= t1) ? 1 : 0;
        c2 += (x >= t2) ? 1 : 0;
      }
    uint pk = ((uint)c1 << 16) | (uint)c2;
    pk += (uint)__shfl_xor((int)pk, 16); pk += (uint)__shfl_xor((int)pk, 32);
    if (lane < 16) cntb[it & 1][wv][fr] = pk;
    __syncthreads();
    const uint cc = cntb[it & 1][0][fr] + cntb[it & 1][1][fr] +
                    cntb[it & 1][2][fr] + cntb[it & 1][3][fr];
    const int cc1 = (int)(cc >> 16), cc2 = (int)(cc & 0xFFFFu);
    if (!done) {
      if (cc1 == 102) { done = true; texact = t1; }
      else if (cc2 == 102) { done = true; texact = t2; }
      else if (cc2 > 102) { lo = t2; nlo = cc2; }
      else if (cc1 < 102) { hi = t1; nhi = cc1; }
      else { lo = t1; nlo = cc1; hi = t2; nhi = cc2; }
      const float wdt = hi - lo;
      const float ts = lo + wdt * ((float)(nlo - 102) / (float)(nlo - nhi));
      const float tm = lo + 0.5f * wdt;
      t1 = fminf(ts, tm); t2 = fmaxf(ts, tm);
      t1 = fminf(fmaxf(t1, lo + 0.02f * wdt), hi - 0.02f * wdt);
      t2 = fminf(fmaxf(t2, lo + 0.02f * wdt), hi - 0.02f * wdt);
    }
  }

  const float CEXP = 0.125f * 1.44269504f;   // head_dim^-0.5 * log2(e)
  const uint64_t anymask = __ballot(!done);  // identical across waves
  float es = 0.f;
  if (anymask == 0ull) {
    // ---- fast path: fused keep+exp, unnormalized, in place
#pragma unroll
    for (int tt = 0; tt < 16; ++tt)
#pragma unroll
      for (int r = 0; r < 4; ++r) {
        const float x = v2[tt][r];
        const float e = (x >= texact) ? exp2f((x - M) * CEXP) : 0.0f;
        v2[tt][r] = e; es += e;
      }
  } else {
    // ---- rare fallback: keep >= thr exactly (recount, no stale-bracket
    // assumption), fill remaining from band [lo,thr) in deterministic
    // (wave, q, tt, r) order via prefix sums.
    uint64_t kmask = 0ull;
    const float thr = done ? texact : hi;
    int bc = 0, tc = 0;
#pragma unroll
    for (int tt = 0; tt < 16; ++tt)
#pragma unroll
      for (int r = 0; r < 4; ++r) {
        const float x = v2[tt][r];
        if (x >= thr) { kmask |= 1ull << (tt * 4 + r); ++tc; }
        bc += (!done && x >= lo && x < thr) ? 1 : 0;
      }
    uint pk2 = ((uint)tc << 16) | (uint)bc;
    pk2 += (uint)__shfl_xor((int)pk2, 16); pk2 += (uint)__shfl_xor((int)pk2, 32);
    if (lane < 16) fcnt[wv][fr] = pk2;
    __syncthreads();
    if (!done) {
      const uint ft = fcnt[0][fr] + fcnt[1][fr] + fcnt[2][fr] + fcnt[3][fr];
      const int tct = (int)(ft >> 16);            // exact count(>=thr)
      int pre = 0;
#pragma unroll
      for (int w = 0; w < 4; ++w) if (w < wv) pre += (int)(fcnt[w][fr] & 0xFFFFu);
#pragma unroll
      for (int qq = 0; qq < 3; ++qq) {
        const int ov = __shfl(bc, fr + 16 * qq);
        if (qq < q) pre += ov;
      }
      const int need = 102 - tct;
#pragma unroll
      for (int tt = 0; tt < 16; ++tt)
#pragma unroll
        for (int r = 0; r < 4; ++r) {
          const float x = v2[tt][r];
          if (x >= lo && x < thr) {
            if (pre < need) kmask |= 1ull << (tt * 4 + r);
            ++pre;
          }
        }
    }
#pragma unroll
    for (int tt = 0; tt < 16; ++tt)
#pragma unroll
      for (int r = 0; r < 4; ++r) {
        const float e = ((kmask >> (tt * 4 + r)) & 1ull)
                        ? exp2f((v2[tt][r] - M) * CEXP) : 0.0f;
        v2[tt][r] = e; es += e;
      }
  }

  // ---- exp-sum partials + unnormalized P write share ONE barrier
  es += __shfl_xor(es, 16); es += __shfl_xor(es, 32);
  if (lane < 16) esred[wv][fr] = es;

  u16* prow = sP + (size_t)fr * 1032 + wv * 256;
#pragma unroll
  for (int tt = 0; tt < 16; ++tt) {
    uint2 pw;
    pw.x = (uint)f2bf(v2[tt][0]) | ((uint)f2bf(v2[tt][1]) << 16);
    pw.y = (uint)f2bf(v2[tt][2]) | ((uint)f2bf(v2[tt][3]) << 16);
    *(uint2*)(prow + tt * 16 + q * 4) = pw;
  }
  __syncthreads();

  // ---- phase D: O = P V (P from LDS, V^T fragments direct from global vt)
  const u16* vtb = vt + (((size_t)(b * 16 + h)) * 64 + wv * 16 + fr) * 1024 + q * 8;
  const u16* pbase = sP + fr * 1032 + q * 8;
  f32x4 oacc = {};
#pragma unroll
  for (int c = 0; c < 16; ++c) {
    const bf16x8 ap0 = *(const bf16x8*)(pbase + c * 64);
    const bf16x8 ap1 = *(const bf16x8*)(pbase + c * 64 + 32);
    const bf16x8 bv0 = *(const bf16x8*)(vtb + c * 64);
    const bf16x8 bv1 = *(const bf16x8*)(vtb + c * 64 + 32);
    oacc = __builtin_amdgcn_mfma_f32_16x16x32_bf16(ap0, bv0, oacc, 0, 0, 0);
    oacc = __builtin_amdgcn_mfma_f32_16x16x32_bf16(ap1, bv1, oacc, 0, 0, 0);
  }

  // ---- deferred normalization at the output (esred still valid in LDS)
#pragma unroll
  for (int r = 0; r < 4; ++r) {
    const int qq = q * 4 + r;
    const float est = esred[0][qq] + esred[1][qq] + esred[2][qq] + esred[3][qq];
    aout[(row0 + rb * 16 + qq) * 1024 + colQ + wv * 16 + fr] = f2bf(oacc[r] / est);
  }
}

// ---------------------------------------------------------------------------
extern "C" void kernel_launch(void* const* d_in, const int* in_sizes, int n_in,
                              void* d_out, int out_size, void* d_ws, size_t ws_size,
                              hipStream_t stream)
{
  (void)in_sizes; (void)n_in; (void)out_size; (void)ws_size;
  const void* x     = d_in[0];
  const void* ln1w  = d_in[1];
  const void* ln1b  = d_in[2];
  const void* qkvw  = d_in[3];
  const void* qkvb  = d_in[4];
  const void* outw  = d_in[5];
  const void* outb  = d_in[6];
  const void* ln2w  = d_in[7];
  const void* ln2b  = d_in[8];
  const void* w1    = d_in[9];
  const void* b1    = d_in[10];
  const void* w2    = d_in[11];
  const void* b2    = d_in[12];
  const void* mask1 = d_in[13];
  const void* mask2 = d_in[14];

  char* ws = (char*)d_ws;
  const size_t MB = 1ull << 20;
  u16*   xn1    = (u16*)(ws);                 // [0,16) MiB; reused as attn_o
  u16*   qkv    = (u16*)(ws + 16 * MB);       // [16,64) MiB
  u16*   xn2    = qkv;                        // [16,32) after attn
  u16*   w1c    = (u16*)(ws + 32 * MB);       // [32,40)
  u16*   w2c    = (u16*)(ws + 40 * MB);       // [40,48)
  float* x2     = (float*)(ws + 64 * MB);     // [64,96) fp32 residual
  u16*   h1     = (u16*)(ws + 96 * MB);       // [96,160); head reused for wq/wo/vt first
  u16*   wq     = (u16*)(ws + 96 * MB);       // [96,102)
  u16*   wo     = (u16*)(ws + 102 * MB);      // [102,104)
  u16*   vt     = (u16*)(ws + 104 * MB);      // [104,120) V^T, dead before FFN1
  int*   flagp  = (int*)(ws + 160 * MB);
  u16*   attn_o = xn1;

  sniff_k<<<1, 256, 0, stream>>>((const u16*)x, flagp);
  cvt_k<<<3072, 256, 0, stream>>>(qkvw, wq, flagp, 3072 * 1024);
  cvt_k<<<1024, 256, 0, stream>>>(outw, wo, flagp, 1024 * 1024);

  ln_k<false><<<8192, 256, 0, stream>>>(x, ln1w, ln1b, xn1, flagp);
  gemm_bt<0><<<dim3(24, 64), 256, 0, stream>>>(xn1, wq, qkvb, nullptr, nullptr, qkv, 8192, 3072, 1024, flagp);
  vtrans_k<<<2048, 256, 0, stream>>>(qkv, vt);
  attn_k<<<8192, 256, 0, stream>>>(qkv, vt, attn_o);
  gemm_bt<1><<<dim3(8, 64), 256, 0, stream>>>(attn_o, wo, outb, x, nullptr, x2, 8192, 1024, 1024, flagp);

  cvt_k<<<4096, 256, 0, stream>>>(w1, w1c, flagp, 4096 * 1024);
  cvt_k<<<4096, 256, 0, stream>>>(w2, w2c, flagp, 4096 * 1024);

  ln_k<true><<<8192, 256, 0, stream>>>(x2, ln2w, ln2b, xn2, flagp);
  gemm_bt<2><<<dim3(32, 64), 256, 0, stream>>>(xn2, w1c, b1, mask1, nullptr, h1, 8192, 4096, 1024, flagp);
  gemm_bt<3><<<dim3(8, 64), 256, 0, stream>>>(h1, w2c, b2, mask2, x2, d_out, 8192, 1024, 4096, flagp);
}

// Round 6
// 1026.327 us; speedup vs baseline: 1.0159x; 1.0159x over previous
//
#include <hip/hip_runtime.h>
#include <cstdint>
#include <cstddef>

typedef unsigned short u16;
typedef __bf16 bf16x8 __attribute__((ext_vector_type(8)));
typedef float f32x4 __attribute__((ext_vector_type(4)));

#define GLOBAL_AS __attribute__((address_space(1)))
#define LDS_AS    __attribute__((address_space(3)))

__device__ __forceinline__ float bf2f(u16 v) {
  return __builtin_bit_cast(float, (uint32_t)v << 16);
}
__device__ __forceinline__ u16 f2bf(float f) {
  uint32_t u = __builtin_bit_cast(uint32_t, f);
  u += 0x7FFFu + ((u >> 16) & 1u);
  return (u16)(u >> 16);
}
// external (input) scalar load: dtype decided by runtime flag
__device__ __forceinline__ float extload(const void* p, size_t i, int isf) {
  return isf ? ((const float*)p)[i] : bf2f(((const u16*)p)[i]);
}
__device__ __forceinline__ void gl_lds16(const void* g, void* l) {
  __builtin_amdgcn_global_load_lds((const GLOBAL_AS void*)g, (LDS_AS void*)l, 16, 0, 0);
}

// ---------------------------------------------------------------------------
// dtype sniff: bf16 data has exponents <= ~0x81; fp32-misread-as-u16 has
// ~44% of words with exponent >= 0x90. flag=1 -> external dtype fp32.
// ---------------------------------------------------------------------------
__global__ __launch_bounds__(256) void sniff_k(const u16* __restrict__ x, int* __restrict__ flag) {
  const int t = threadIdx.x;
  int cnt = 0;
#pragma unroll
  for (int j = 0; j < 16; ++j) {
    const u16 w = x[t * 16 + j];
    const int e = (w >> 7) & 0xFF;
    cnt += (e >= 0x90) ? 1 : 0;
  }
#pragma unroll
  for (int o = 32; o; o >>= 1) cnt += __shfl_xor(cnt, o);
  __shared__ int red[4];
  if ((t & 63) == 0) red[t >> 6] = cnt;
  __syncthreads();
  if (t == 0) flag[0] = (red[0] + red[1] + red[2] + red[3] > 16) ? 1 : 0;
}

// canonicalize weight matrix to bf16 (copy if already bf16)
__global__ __launch_bounds__(256) void cvt_k(const void* __restrict__ in, u16* __restrict__ out,
                                             const int* __restrict__ flagp, int n) {
  const int i = (blockIdx.x * 256 + threadIdx.x) * 4;
  if (i >= n) return;
  if (*flagp) {
    const float4 v = *(const float4*)((const float*)in + i);
    out[i] = f2bf(v.x); out[i + 1] = f2bf(v.y); out[i + 2] = f2bf(v.z); out[i + 3] = f2bf(v.w);
  } else {
    *(ushort4*)(out + i) = *(const ushort4*)((const u16*)in + i);
  }
}

// ---------------------------------------------------------------------------
// LayerNorm row of 1024. INTF32: input is internal fp32 ws; else external (flag).
// ---------------------------------------------------------------------------
template<bool INTF32>
__global__ __launch_bounds__(256) void ln_k(const void* __restrict__ inp,
                                            const void* __restrict__ w,
                                            const void* __restrict__ b,
                                            u16* __restrict__ out,
                                            const int* __restrict__ flagp)
{
  const int isf = *flagp;
  const int row = blockIdx.x;
  const int t = threadIdx.x;
  float x0, x1, x2, x3;
  if (INTF32 || isf) {
    const float4 vv = ((const float4*)((const float*)inp + (size_t)row * 1024))[t];
    x0 = vv.x; x1 = vv.y; x2 = vv.z; x3 = vv.w;
  } else {
    const ushort4 vv = ((const ushort4*)((const u16*)inp + (size_t)row * 1024))[t];
    x0 = bf2f(vv.x); x1 = bf2f(vv.y); x2 = bf2f(vv.z); x3 = bf2f(vv.w);
  }
  float s = x0 + x1 + x2 + x3;
  float sq = x0 * x0 + x1 * x1 + x2 * x2 + x3 * x3;
#pragma unroll
  for (int o = 32; o; o >>= 1) { s += __shfl_xor(s, o); sq += __shfl_xor(sq, o); }
  __shared__ float red[8];
  const int wv = t >> 6;
  if ((t & 63) == 0) { red[wv] = s; red[wv + 4] = sq; }
  __syncthreads();
  s = red[0] + red[1] + red[2] + red[3];
  sq = red[4] + red[5] + red[6] + red[7];
  const float mu = s * (1.0f / 1024.0f);
  const float var = sq * (1.0f / 1024.0f) - mu * mu;
  const float rstd = rsqrtf(var + 1e-5f);
  const int c0 = t * 4;
  u16* o4 = out + (size_t)row * 1024 + c0;
  o4[0] = f2bf((x0 - mu) * rstd * extload(w, c0 + 0, isf) + extload(b, c0 + 0, isf));
  o4[1] = f2bf((x1 - mu) * rstd * extload(w, c0 + 1, isf) + extload(b, c0 + 1, isf));
  o4[2] = f2bf((x2 - mu) * rstd * extload(w, c0 + 2, isf) + extload(b, c0 + 2, isf));
  o4[3] = f2bf((x3 - mu) * rstd * extload(w, c0 + 3, isf) + extload(b, c0 + 3, isf));
}

// ---------------------------------------------------------------------------
// bf16 GEMM: out[m,n] = sum_k A[m,k]*B[n,k]  (both K-contiguous, internal bf16).
// v2: T3-minimum single-barrier double-buffered pipeline (catalog §5.5):
// prologue-stage buf0; per K-tile issue next-tile global_load_lds into buf^1
// BEFORE compute, compute from buf, then ONE vmcnt(0)+barrier. Loads fly
// under ds_read+MFMA; barriers per tile 2 -> 1.
// EPI 0: out bf16 = acc + bias
// EPI 1: out fp32 = acc + bias + ext(auxb)            (residual to fp32 ws)
// EPI 2: out bf16 = relu(acc + bias) * (ext(auxb)>0.5)
// EPI 3: out EXT  = intf32(auxf) + (acc + bias) * (ext(auxb)>0.5)
// ---------------------------------------------------------------------------
template<int EPI>
__global__ __launch_bounds__(256, 2) void gemm_bt(
    const u16* __restrict__ A, const u16* __restrict__ B,
    const void* __restrict__ bias, const void* __restrict__ auxb,
    const float* __restrict__ auxf, void* __restrict__ outp,
    int M, int N, int K, const int* __restrict__ flagp)
{
  __shared__ u16 sA[2][128 * 32];
  __shared__ u16 sB[2][128 * 32];
  const int t = threadIdx.x;
  const int lane = t & 63;
  const int wv = t >> 6;
  const int wm = (wv >> 1) << 6;
  const int wn = (wv & 1) << 6;
  const int bm = blockIdx.y << 7;
  const int bn = blockIdx.x << 7;

  f32x4 acc[4][4] = {};

  const int ldr = t >> 2;     // staging row 0..63 (+64 for i=1)
  const int lseg = t & 3;     // physical 16B segment slot
  const int fr = lane & 15;
  const int q = lane >> 4;

  const int nt = K >> 5;      // K/32 tiles

  // stage one 128x32 A-tile + B-tile into buffer `buf` (4 gl_lds16 / thread)
#define STAGE(buf, kt)                                                          \
  {                                                                             \
    _Pragma("unroll")                                                           \
    for (int i = 0; i < 2; ++i) {                                               \
      const int r = ldr + (i << 6);                                             \
      const int sl = lseg ^ ((r >> 1) & 3);   /* XOR seg swizzle */             \
      gl_lds16(A + (size_t)(bm + r) * K + (kt) + (sl << 3),                     \
               &sA[buf][(((i << 8) + t) << 3)]);                                \
      gl_lds16(B + (size_t)(bn + r) * K + (kt) + (sl << 3),                     \
               &sB[buf][(((i << 8) + t) << 3)]);                                \
    }                                                                           \
  }

  STAGE(0, 0);
  asm volatile("s_waitcnt vmcnt(0)" ::: "memory");
  __syncthreads();

  int cur = 0;
  for (int kt_i = 0; kt_i < nt; ++kt_i) {
    const bool more = (kt_i + 1 < nt);
    if (more) STAGE(cur ^ 1, (kt_i + 1) << 5);   // issue next tile (flies under compute)

    bf16x8 af[4], bfv[4];
#pragma unroll
    for (int i = 0; i < 4; ++i) {
      const int rr = wm + (i << 4) + fr;
      af[i] = *(const bf16x8*)&sA[cur][(rr << 5) + ((q ^ ((rr >> 1) & 3)) << 3)];
      const int nn = wn + (i << 4) + fr;
      bfv[i] = *(const bf16x8*)&sB[cur][(nn << 5) + ((q ^ ((nn >> 1) & 3)) << 3)];
    }
#pragma unroll
    for (int mi = 0; mi < 4; ++mi)
#pragma unroll
      for (int ni = 0; ni < 4; ++ni)
        acc[mi][ni] = __builtin_amdgcn_mfma_f32_16x16x32_bf16(af[mi], bfv[ni], acc[mi][ni], 0, 0, 0);

    if (more) {
      asm volatile("s_waitcnt vmcnt(0)" ::: "memory");   // next tile landed
      __syncthreads();                                    // all waves done read+land
      cur ^= 1;
    }
  }
#undef STAGE

  const int isf = *flagp;
#pragma unroll
  for (int mi = 0; mi < 4; ++mi) {
#pragma unroll
    for (int ni = 0; ni < 4; ++ni) {
#pragma unroll
      for (int r = 0; r < 4; ++r) {
        const int gm = bm + wm + (mi << 4) + (q << 2) + r;
        const int gn = bn + wn + (ni << 4) + fr;
        const size_t idx = (size_t)gm * N + gn;
        float v = acc[mi][ni][r] + extload(bias, gn, isf);
        if (EPI == 0) {
          ((u16*)outp)[idx] = f2bf(v);
        } else if (EPI == 1) {
          ((float*)outp)[idx] = v + extload(auxb, idx, isf);
        } else if (EPI == 2) {
          const float keep = extload(auxb, idx, isf) > 0.5f ? 1.0f : 0.0f;
          ((u16*)outp)[idx] = f2bf(fmaxf(v, 0.0f) * keep);
        } else {
          const float keep = extload(auxb, idx, isf) > 0.5f ? 1.0f : 0.0f;
          const float o = auxf[idx] + v * keep;
          if (isf) ((float*)outp)[idx] = o;
          else     ((u16*)outp)[idx] = f2bf(o);
        }
      }
    }
  }
}

// ---------------------------------------------------------------------------
// V transpose: vt[b][h][d][n] = qkv[b*1024+n][2048 + h*64 + d]  (bf16)
// block = one (b,h,ntile of 64 keys); 64x64 tile via LDS.
// ---------------------------------------------------------------------------
__global__ __launch_bounds__(256) void vtrans_k(const u16* __restrict__ qkv,
                                                u16* __restrict__ vt)
{
  __shared__ u16 tile[64][72];
  const int blk = blockIdx.x;
  const int nt = blk & 15, h = (blk >> 4) & 15, b = blk >> 8;
  const int t = threadIdx.x;
#pragma unroll
  for (int it = 0; it < 2; ++it) {
    const int li = it * 256 + t, r = li >> 3, sg = li & 7;
    const uint4 g = *(const uint4*)(qkv + ((size_t)b * 1024 + nt * 64 + r) * 3072 + 2048 + h * 64 + sg * 8);
    *(uint4*)&tile[r][sg * 8] = g;
  }
  __syncthreads();
#pragma unroll
  for (int it = 0; it < 2; ++it) {
    const int li = it * 256 + t, d = li >> 3, sg = li & 7;
    u16 tmp[8];
#pragma unroll
    for (int j = 0; j < 8; ++j) tmp[j] = tile[sg * 8 + j][d];
    *(uint4*)(vt + (((size_t)(b * 16 + h)) * 64 + d) * 1024 + nt * 64 + sg * 8) = *(const uint4*)tmp;
  }
}

// ---------------------------------------------------------------------------
// Fused sparse attention (exact round-1 kernel, proven 323 us / WRITE 16 MB):
// swapped QK^T keeps all 1024 scores of each query register-resident (lane fr
// owns query fr; keys split 256/wave). LDS = bf16 P + ~2KB scratch -> 4
// blocks/CU. The v3 selection rewrite (mu/sigma bracket, dual-threshold,
// deferred normalization) REGRESSED on HW: +140 MB HBM writes (r3/r5 A/B,
// independent of V-prefetch) -> reverted wholesale.
// ---------------------------------------------------------------------------
__global__ __launch_bounds__(256, 4) void attn_k(const u16* __restrict__ qkv,
                                                 const u16* __restrict__ vt,
                                                 u16* __restrict__ aout)
{
  __shared__ u16 sP[16 * 1032];          // P bf16 [query][key], stride 1032
  __shared__ float4 red4[4][16];         // per-wave stats {mx,mn,sm,sq}
  __shared__ uint cntb[2][4][16];        // bisection counts (double-buffered)
  __shared__ uint fcnt[4][16];           // fallback band counts
  __shared__ float esred[4][16];         // exp-sum partials

  const int t = threadIdx.x;
  const int lane = t & 63;
  const int wv = t >> 6;
  const int bid = blockIdx.x;
  const int sw = ((bid & 7) << 10) | (bid >> 3);   // bijective XCD swizzle (8192 = 8*1024)
  const int bh = sw >> 6;
  const int rb = sw & 63;
  const int b = bh >> 4, h = bh & 15;
  const size_t row0 = (size_t)b * 1024;
  const int colQ = h * 64;
  const int fr = lane & 15, q = lane >> 4;

  // Q fragments (B operand of swapped mfma): rows fr = query
  const u16* qrow = qkv + (row0 + rb * 16 + fr) * 3072 + colQ + q * 8;
  const bf16x8 bq0 = *(const bf16x8*)(qrow);
  const bf16x8 bq1 = *(const bf16x8*)(qrow + 32);

  // ---- phase B: swapped scores. Wave wv owns keys [wv*256, wv*256+256).
  // v2[tt][r] = score[key = wv*256 + tt*16 + q*4 + r][query = fr]
  float v2[16][4];
  const u16* kbase = qkv + (row0 + wv * 256 + fr) * 3072 + 1024 + colQ + q * 8;
#pragma unroll
  for (int tt = 0; tt < 16; ++tt) {
    const u16* kp = kbase + (size_t)tt * 16 * 3072;
    const bf16x8 ak0 = *(const bf16x8*)(kp);
    const bf16x8 ak1 = *(const bf16x8*)(kp + 32);
    f32x4 sacc = {};
    sacc = __builtin_amdgcn_mfma_f32_16x16x32_bf16(ak0, bq0, sacc, 0, 0, 0);
    sacc = __builtin_amdgcn_mfma_f32_16x16x32_bf16(ak1, bq1, sacc, 0, 0, 0);
#pragma unroll
    for (int r = 0; r < 4; ++r) v2[tt][r] = sacc[r];
  }

  // ---- phase C: per-query stats (lane's 64 values all belong to query fr)
  float mx = v2[0][0], mn = v2[0][0], sm = 0.f, sq = 0.f;
#pragma unroll
  for (int tt = 0; tt < 16; ++tt)
#pragma unroll
    for (int r = 0; r < 4; ++r) {
      const float x = v2[tt][r];
      mx = fmaxf(mx, x); mn = fminf(mn, x); sm += x; sq += x * x;
    }
  // combine the 4 q-lanes of this query within the wave (lanes fr+16q)
  mx = fmaxf(mx, __shfl_xor(mx, 16)); mx = fmaxf(mx, __shfl_xor(mx, 32));
  mn = fminf(mn, __shfl_xor(mn, 16)); mn = fminf(mn, __shfl_xor(mn, 32));
  sm += __shfl_xor(sm, 16); sm += __shfl_xor(sm, 32);
  sq += __shfl_xor(sq, 16); sq += __shfl_xor(sq, 32);
  if (lane < 16) red4[wv][fr] = make_float4(mx, mn, sm, sq);
  __syncthreads();
  {
    const float4 a0 = red4[0][fr], a1 = red4[1][fr], a2 = red4[2][fr], a3 = red4[3][fr];
    mx = fmaxf(fmaxf(a0.x, a1.x), fmaxf(a2.x, a3.x));
    mn = fminf(fminf(a0.y, a1.y), fminf(a2.y, a3.y));
    sm = a0.z + a1.z + a2.z + a3.z;
    sq = a0.w + a1.w + a2.w + a3.w;
  }

  // ---- top-102 threshold search (same numerics as proven version)
  float lo, hi, tcur, texact = 0.f;
  int nlo = 1024, nhi = 0;
  bool done = false;
  {
    const float mu = sm * (1.0f / 1024.0f);
    const float var = fmaxf(sq * (1.0f / 1024.0f) - mu * mu, 0.0f);
    const float sd = sqrtf(var + 1e-20f);
    lo = mn - fabsf(mn) * 1e-6f - 1e-12f;
    hi = mx + fabsf(mx) * 1e-6f + 1e-12f;
    const float t0 = mu + 1.2816f * sd;            // Gaussian 10% upper-quantile seed
    const float wdt = hi - lo;
    tcur = fminf(fmaxf(t0, lo + 0.02f * wdt), hi - 0.02f * wdt);
  }

  for (int it = 0; it < 10; ++it) {
    if (__ballot(!done) == 0ull) break;            // identical across waves
    int c_ = 0;
#pragma unroll
    for (int tt = 0; tt < 16; ++tt)
#pragma unroll
      for (int r = 0; r < 4; ++r) c_ += (v2[tt][r] >= tcur) ? 1 : 0;
    c_ += __shfl_xor(c_, 16); c_ += __shfl_xor(c_, 32);
    if (lane < 16) cntb[it & 1][wv][fr] = (uint)c_;
    __syncthreads();
    const int cc = (int)(cntb[it & 1][0][fr] + cntb[it & 1][1][fr] +
                         cntb[it & 1][2][fr] + cntb[it & 1][3][fr]);
    if (!done) {
      if (cc == 102) { done = true; texact = tcur; }
      else if (cc > 102) { lo = tcur; nlo = cc; }
      else { hi = tcur; nhi = cc; }
      float tn;
      if (it & 1) tn = 0.5f * (lo + hi);
      else {
        const float den = (float)(nlo - nhi);
        tn = lo + (hi - lo) * ((float)(nlo - 102) / den);
      }
      const float wdt = hi - lo;
      tcur = fminf(fmaxf(tn, lo + 0.02f * wdt), hi - 0.02f * wdt);
    }
  }

  // ---- build keep-mask (64 bits, bit = tt*4+r)
  uint64_t kmask = 0ull;
  const uint64_t anymask = __ballot(!done);        // identical across waves
  if (anymask == 0ull) {
#pragma unroll
    for (int tt = 0; tt < 16; ++tt)
#pragma unroll
      for (int r = 0; r < 4; ++r)
        if (v2[tt][r] >= texact) kmask |= 1ull << (tt * 4 + r);
  } else {
    // rare fallback: keep all >= hi, fill remaining from band [lo,hi) in
    // deterministic (wave, q, tt, r) order via cross-lane prefix sums.
    const float thr = done ? texact : hi;
    int bc = 0;
#pragma unroll
    for (int tt = 0; tt < 16; ++tt)
#pragma unroll
      for (int r = 0; r < 4; ++r) {
        const float x = v2[tt][r];
        if (x >= thr) kmask |= 1ull << (tt * 4 + r);
        bc += (!done && x >= lo && x < hi) ? 1 : 0;
      }
    int bw = bc + __shfl_xor(bc, 16);
    bw += __shfl_xor(bw, 32);
    if (lane < 16) fcnt[wv][fr] = (uint)bw;
    __syncthreads();
    if (!done) {
      int pre = 0;
#pragma unroll
      for (int w = 0; w < 4; ++w) if (w < wv) pre += (int)fcnt[w][fr];
#pragma unroll
      for (int qq = 0; qq < 3; ++qq) {
        const int ov = __shfl(bc, fr + 16 * qq);
        if (qq < q) pre += ov;
      }
      const int need = 102 - nhi;
#pragma unroll
      for (int tt = 0; tt < 16; ++tt)
#pragma unroll
        for (int r = 0; r < 4; ++r) {
          const float x = v2[tt][r];
          if (x >= lo && x < hi) {
            if (pre < need) kmask |= 1ull << (tt * 4 + r);
            ++pre;
          }
        }
    }
  }

  // ---- exp + normalize (overwrite v2 in place), cross-wave denominator
  const float CEXP = 0.125f * 1.44269504f;   // head_dim^-0.5 * log2(e)
  float es = 0.f;
#pragma unroll
  for (int tt = 0; tt < 16; ++tt)
#pragma unroll
    for (int r = 0; r < 4; ++r) {
      const float e = ((kmask >> (tt * 4 + r)) & 1ull) ? exp2f((v2[tt][r] - mx) * CEXP) : 0.0f;
      v2[tt][r] = e;
      es += e;
    }
  es += __shfl_xor(es, 16); es += __shfl_xor(es, 32);
  if (lane < 16) esred[wv][fr] = es;
  __syncthreads();
  const float inv = 1.0f / (esred[0][fr] + esred[1][fr] + esred[2][fr] + esred[3][fr]);

  // ---- write P (bf16, packed pairs along r)
  u16* prow = sP + (size_t)fr * 1032 + wv * 256;
#pragma unroll
  for (int tt = 0; tt < 16; ++tt) {
#pragma unroll
    for (int rp = 0; rp < 2; ++rp) {
      const u16 p0 = f2bf(v2[tt][2 * rp] * inv);
      const u16 p1 = f2bf(v2[tt][2 * rp + 1] * inv);
      *(uint*)(prow + tt * 16 + q * 4 + 2 * rp) = (uint)p0 | ((uint)p1 << 16);
    }
  }
  __syncthreads();

  // ---- phase D: O = P V (P from LDS, V^T fragments direct from global vt)
  const u16* vtb = vt + (((size_t)(b * 16 + h)) * 64 + wv * 16 + fr) * 1024 + q * 8;
  const u16* pbase = sP + fr * 1032 + q * 8;
  f32x4 oacc = {};
#pragma unroll
  for (int c = 0; c < 16; ++c) {
    const bf16x8 ap0 = *(const bf16x8*)(pbase + c * 64);
    const bf16x8 ap1 = *(const bf16x8*)(pbase + c * 64 + 32);
    const bf16x8 bv0 = *(const bf16x8*)(vtb + c * 64);
    const bf16x8 bv1 = *(const bf16x8*)(vtb + c * 64 + 32);
    oacc = __builtin_amdgcn_mfma_f32_16x16x32_bf16(ap0, bv0, oacc, 0, 0, 0);
    oacc = __builtin_amdgcn_mfma_f32_16x16x32_bf16(ap1, bv1, oacc, 0, 0, 0);
  }
#pragma unroll
  for (int r = 0; r < 4; ++r)
    aout[(row0 + rb * 16 + q * 4 + r) * 1024 + colQ + wv * 16 + fr] = f2bf(oacc[r]);
}

// ---------------------------------------------------------------------------
extern "C" void kernel_launch(void* const* d_in, const int* in_sizes, int n_in,
                              void* d_out, int out_size, void* d_ws, size_t ws_size,
                              hipStream_t stream)
{
  (void)in_sizes; (void)n_in; (void)out_size; (void)ws_size;
  const void* x     = d_in[0];
  const void* ln1w  = d_in[1];
  const void* ln1b  = d_in[2];
  const void* qkvw  = d_in[3];
  const void* qkvb  = d_in[4];
  const void* outw  = d_in[5];
  const void* outb  = d_in[6];
  const void* ln2w  = d_in[7];
  const void* ln2b  = d_in[8];
  const void* w1    = d_in[9];
  const void* b1    = d_in[10];
  const void* w2    = d_in[11];
  const void* b2    = d_in[12];
  const void* mask1 = d_in[13];
  const void* mask2 = d_in[14];

  char* ws = (char*)d_ws;
  const size_t MB = 1ull << 20;
  u16*   xn1    = (u16*)(ws);                 // [0,16) MiB; reused as attn_o
  u16*   qkv    = (u16*)(ws + 16 * MB);       // [16,64) MiB
  u16*   xn2    = qkv;                        // [16,32) after attn
  u16*   w1c    = (u16*)(ws + 32 * MB);       // [32,40)
  u16*   w2c    = (u16*)(ws + 40 * MB);       // [40,48)
  float* x2     = (float*)(ws + 64 * MB);     // [64,96) fp32 residual
  u16*   h1     = (u16*)(ws + 96 * MB);       // [96,160); head reused for wq/wo/vt first
  u16*   wq     = (u16*)(ws + 96 * MB);       // [96,102)
  u16*   wo     = (u16*)(ws + 102 * MB);      // [102,104)
  u16*   vt     = (u16*)(ws + 104 * MB);      // [104,120) V^T, dead before FFN1
  int*   flagp  = (int*)(ws + 160 * MB);
  u16*   attn_o = xn1;

  sniff_k<<<1, 256, 0, stream>>>((const u16*)x, flagp);
  cvt_k<<<3072, 256, 0, stream>>>(qkvw, wq, flagp, 3072 * 1024);
  cvt_k<<<1024, 256, 0, stream>>>(outw, wo, flagp, 1024 * 1024);

  ln_k<false><<<8192, 256, 0, stream>>>(x, ln1w, ln1b, xn1, flagp);
  gemm_bt<0><<<dim3(24, 64), 256, 0, stream>>>(xn1, wq, qkvb, nullptr, nullptr, qkv, 8192, 3072, 1024, flagp);
  vtrans_k<<<2048, 256, 0, stream>>>(qkv, vt);
  attn_k<<<8192, 256, 0, stream>>>(qkv, vt, attn_o);
  gemm_bt<1><<<dim3(8, 64), 256, 0, stream>>>(attn_o, wo, outb, x, nullptr, x2, 8192, 1024, 1024, flagp);

  cvt_k<<<4096, 256, 0, stream>>>(w1, w1c, flagp, 4096 * 1024);
  cvt_k<<<4096, 256, 0, stream>>>(w2, w2c, flagp, 4096 * 1024);

  ln_k<true><<<8192, 256, 0, stream>>>(x2, ln2w, ln2b, xn2, flagp);
  gemm_bt<2><<<dim3(32, 64), 256, 0, stream>>>(xn2, w1c, b1, mask1, nullptr, h1, 8192, 4096, 1024, flagp);
  gemm_bt<3><<<dim3(8, 64), 256, 0, stream>>>(h1, w2c, b2, mask2, x2, d_out, 8192, 1024, 4096, flagp);
}

// Round 7
// 1001.895 us; speedup vs baseline: 1.0407x; 1.0244x over previous
//
#include <hip/hip_runtime.h>
#include <cstdint>
#include <cstddef>

typedef unsigned short u16;
typedef __bf16 bf16x8 __attribute__((ext_vector_type(8)));
typedef float f32x4 __attribute__((ext_vector_type(4)));

#define GLOBAL_AS __attribute__((address_space(1)))
#define LDS_AS    __attribute__((address_space(3)))

__device__ __forceinline__ float bf2f(u16 v) {
  return __builtin_bit_cast(float, (uint32_t)v << 16);
}
__device__ __forceinline__ u16 f2bf(float f) {
  uint32_t u = __builtin_bit_cast(uint32_t, f);
  u += 0x7FFFu + ((u >> 16) & 1u);
  return (u16)(u >> 16);
}
// external (input) scalar load: dtype decided by runtime flag
__device__ __forceinline__ float extload(const void* p, size_t i, int isf) {
  return isf ? ((const float*)p)[i] : bf2f(((const u16*)p)[i]);
}
__device__ __forceinline__ void gl_lds16(const void* g, void* l) {
  __builtin_amdgcn_global_load_lds((const GLOBAL_AS void*)g, (LDS_AS void*)l, 16, 0, 0);
}

// ---------------------------------------------------------------------------
// dtype sniff: bf16 data has exponents <= ~0x81; fp32-misread-as-u16 has
// ~44% of words with exponent >= 0x90. flag=1 -> external dtype fp32.
// ---------------------------------------------------------------------------
__global__ __launch_bounds__(256) void sniff_k(const u16* __restrict__ x, int* __restrict__ flag) {
  const int t = threadIdx.x;
  int cnt = 0;
#pragma unroll
  for (int j = 0; j < 16; ++j) {
    const u16 w = x[t * 16 + j];
    const int e = (w >> 7) & 0xFF;
    cnt += (e >= 0x90) ? 1 : 0;
  }
#pragma unroll
  for (int o = 32; o; o >>= 1) cnt += __shfl_xor(cnt, o);
  __shared__ int red[4];
  if ((t & 63) == 0) red[t >> 6] = cnt;
  __syncthreads();
  if (t == 0) flag[0] = (red[0] + red[1] + red[2] + red[3] > 16) ? 1 : 0;
}

// canonicalize weight matrix to bf16 (copy if already bf16)
__global__ __launch_bounds__(256) void cvt_k(const void* __restrict__ in, u16* __restrict__ out,
                                             const int* __restrict__ flagp, int n) {
  const int i = (blockIdx.x * 256 + threadIdx.x) * 4;
  if (i >= n) return;
  if (*flagp) {
    const float4 v = *(const float4*)((const float*)in + i);
    out[i] = f2bf(v.x); out[i + 1] = f2bf(v.y); out[i + 2] = f2bf(v.z); out[i + 3] = f2bf(v.w);
  } else {
    *(ushort4*)(out + i) = *(const ushort4*)((const u16*)in + i);
  }
}

// ---------------------------------------------------------------------------
// LayerNorm row of 1024. INTF32: input is internal fp32 ws; else external (flag).
// ---------------------------------------------------------------------------
template<bool INTF32>
__global__ __launch_bounds__(256) void ln_k(const void* __restrict__ inp,
                                            const void* __restrict__ w,
                                            const void* __restrict__ b,
                                            u16* __restrict__ out,
                                            const int* __restrict__ flagp)
{
  const int isf = *flagp;
  const int row = blockIdx.x;
  const int t = threadIdx.x;
  float x0, x1, x2, x3;
  if (INTF32 || isf) {
    const float4 vv = ((const float4*)((const float*)inp + (size_t)row * 1024))[t];
    x0 = vv.x; x1 = vv.y; x2 = vv.z; x3 = vv.w;
  } else {
    const ushort4 vv = ((const ushort4*)((const u16*)inp + (size_t)row * 1024))[t];
    x0 = bf2f(vv.x); x1 = bf2f(vv.y); x2 = bf2f(vv.z); x3 = bf2f(vv.w);
  }
  float s = x0 + x1 + x2 + x3;
  float sq = x0 * x0 + x1 * x1 + x2 * x2 + x3 * x3;
#pragma unroll
  for (int o = 32; o; o >>= 1) { s += __shfl_xor(s, o); sq += __shfl_xor(sq, o); }
  __shared__ float red[8];
  const int wv = t >> 6;
  if ((t & 63) == 0) { red[wv] = s; red[wv + 4] = sq; }
  __syncthreads();
  s = red[0] + red[1] + red[2] + red[3];
  sq = red[4] + red[5] + red[6] + red[7];
  const float mu = s * (1.0f / 1024.0f);
  const float var = sq * (1.0f / 1024.0f) - mu * mu;
  const float rstd = rsqrtf(var + 1e-5f);
  const int c0 = t * 4;
  u16* o4 = out + (size_t)row * 1024 + c0;
  o4[0] = f2bf((x0 - mu) * rstd * extload(w, c0 + 0, isf) + extload(b, c0 + 0, isf));
  o4[1] = f2bf((x1 - mu) * rstd * extload(w, c0 + 1, isf) + extload(b, c0 + 1, isf));
  o4[2] = f2bf((x2 - mu) * rstd * extload(w, c0 + 2, isf) + extload(b, c0 + 2, isf));
  o4[3] = f2bf((x3 - mu) * rstd * extload(w, c0 + 3, isf) + extload(b, c0 + 3, isf));
}

// ---------------------------------------------------------------------------
// bf16 GEMM: out[m,n] = sum_k A[m,k]*B[n,k]  (both K-contiguous, internal bf16).
// v3: + __launch_bounds__(256,4): LDS is 32KB/block (permits 5/CU) but the
//     old (256,2) declaration let VGPR float above 128 -> only 2-3 resident.
//     4 resident blocks/CU = 2x waves to hide the per-K-tile vmcnt+barrier
//     drain (m114 inter-block overlap mechanism).
//     + bijective XCD swizzle (T1): all grids %8==0. Each XCD gets a
//     contiguous x-major chunk -> A-tile refetch /8, B panel L2-resident.
// EPI 0: out bf16 = acc + bias
// EPI 1: out fp32 = acc + bias + ext(auxb)            (residual to fp32 ws)
// EPI 2: out bf16 = relu(acc + bias) * (ext(auxb)>0.5)
// EPI 3: out EXT  = intf32(auxf) + (acc + bias) * (ext(auxb)>0.5)
// ---------------------------------------------------------------------------
template<int EPI>
__global__ __launch_bounds__(256, 4) void gemm_bt(
    const u16* __restrict__ A, const u16* __restrict__ B,
    const void* __restrict__ bias, const void* __restrict__ auxb,
    const float* __restrict__ auxf, void* __restrict__ outp,
    int M, int N, int K, const int* __restrict__ flagp)
{
  __shared__ u16 sA[2][128 * 32];
  __shared__ u16 sB[2][128 * 32];
  const int t = threadIdx.x;
  const int lane = t & 63;
  const int wv = t >> 6;
  const int wm = (wv >> 1) << 6;
  const int wn = (wv & 1) << 6;

  // bijective XCD swizzle on the linear block id (nwg % 8 == 0 for all
  // launches here): XCD k owns the contiguous swz range [k*cpx,(k+1)*cpx).
  const int nx = gridDim.x;
  const int nwg = nx * gridDim.y;
  const int lin = blockIdx.y * nx + blockIdx.x;
  const int cpx = nwg >> 3;
  const int swz = (lin & 7) * cpx + (lin >> 3);
  const int bm = (swz / nx) << 7;
  const int bn = (swz % nx) << 7;

  f32x4 acc[4][4] = {};

  const int ldr = t >> 2;     // staging row 0..63 (+64 for i=1)
  const int lseg = t & 3;     // physical 16B segment slot
  const int fr = lane & 15;
  const int q = lane >> 4;

  const int nt = K >> 5;      // K/32 tiles

  // stage one 128x32 A-tile + B-tile into buffer `buf` (4 gl_lds16 / thread)
#define STAGE(buf, kt)                                                          \
  {                                                                             \
    _Pragma("unroll")                                                           \
    for (int i = 0; i < 2; ++i) {                                               \
      const int r = ldr + (i << 6);                                             \
      const int sl = lseg ^ ((r >> 1) & 3);   /* XOR seg swizzle */             \
      gl_lds16(A + (size_t)(bm + r) * K + (kt) + (sl << 3),                     \
               &sA[buf][(((i << 8) + t) << 3)]);                                \
      gl_lds16(B + (size_t)(bn + r) * K + (kt) + (sl << 3),                     \
               &sB[buf][(((i << 8) + t) << 3)]);                                \
    }                                                                           \
  }

  STAGE(0, 0);
  asm volatile("s_waitcnt vmcnt(0)" ::: "memory");
  __syncthreads();

  int cur = 0;
  for (int kt_i = 0; kt_i < nt; ++kt_i) {
    const bool more = (kt_i + 1 < nt);
    if (more) STAGE(cur ^ 1, (kt_i + 1) << 5);   // issue next tile (flies under compute)

    bf16x8 af[4], bfv[4];
#pragma unroll
    for (int i = 0; i < 4; ++i) {
      const int rr = wm + (i << 4) + fr;
      af[i] = *(const bf16x8*)&sA[cur][(rr << 5) + ((q ^ ((rr >> 1) & 3)) << 3)];
      const int nn = wn + (i << 4) + fr;
      bfv[i] = *(const bf16x8*)&sB[cur][(nn << 5) + ((q ^ ((nn >> 1) & 3)) << 3)];
    }
#pragma unroll
    for (int mi = 0; mi < 4; ++mi)
#pragma unroll
      for (int ni = 0; ni < 4; ++ni)
        acc[mi][ni] = __builtin_amdgcn_mfma_f32_16x16x32_bf16(af[mi], bfv[ni], acc[mi][ni], 0, 0, 0);

    if (more) {
      asm volatile("s_waitcnt vmcnt(0)" ::: "memory");   // next tile landed
      __syncthreads();                                    // all waves done read+land
      cur ^= 1;
    }
  }
#undef STAGE

  const int isf = *flagp;
#pragma unroll
  for (int mi = 0; mi < 4; ++mi) {
#pragma unroll
    for (int ni = 0; ni < 4; ++ni) {
#pragma unroll
      for (int r = 0; r < 4; ++r) {
        const int gm = bm + wm + (mi << 4) + (q << 2) + r;
        const int gn = bn + wn + (ni << 4) + fr;
        const size_t idx = (size_t)gm * N + gn;
        float v = acc[mi][ni][r] + extload(bias, gn, isf);
        if (EPI == 0) {
          ((u16*)outp)[idx] = f2bf(v);
        } else if (EPI == 1) {
          ((float*)outp)[idx] = v + extload(auxb, idx, isf);
        } else if (EPI == 2) {
          const float keep = extload(auxb, idx, isf) > 0.5f ? 1.0f : 0.0f;
          ((u16*)outp)[idx] = f2bf(fmaxf(v, 0.0f) * keep);
        } else {
          const float keep = extload(auxb, idx, isf) > 0.5f ? 1.0f : 0.0f;
          const float o = auxf[idx] + v * keep;
          if (isf) ((float*)outp)[idx] = o;
          else     ((u16*)outp)[idx] = f2bf(o);
        }
      }
    }
  }
}

// ---------------------------------------------------------------------------
// V transpose: vt[b][h][d][n] = qkv[b*1024+n][2048 + h*64 + d]  (bf16)
// block = one (b,h,ntile of 64 keys); 64x64 tile via LDS.
// ---------------------------------------------------------------------------
__global__ __launch_bounds__(256) void vtrans_k(const u16* __restrict__ qkv,
                                                u16* __restrict__ vt)
{
  __shared__ u16 tile[64][72];
  const int blk = blockIdx.x;
  const int nt = blk & 15, h = (blk >> 4) & 15, b = blk >> 8;
  const int t = threadIdx.x;
#pragma unroll
  for (int it = 0; it < 2; ++it) {
    const int li = it * 256 + t, r = li >> 3, sg = li & 7;
    const uint4 g = *(const uint4*)(qkv + ((size_t)b * 1024 + nt * 64 + r) * 3072 + 2048 + h * 64 + sg * 8);
    *(uint4*)&tile[r][sg * 8] = g;
  }
  __syncthreads();
#pragma unroll
  for (int it = 0; it < 2; ++it) {
    const int li = it * 256 + t, d = li >> 3, sg = li & 7;
    u16 tmp[8];
#pragma unroll
    for (int j = 0; j < 8; ++j) tmp[j] = tile[sg * 8 + j][d];
    *(uint4*)(vt + (((size_t)(b * 16 + h)) * 64 + d) * 1024 + nt * 64 + sg * 8) = *(const uint4*)tmp;
  }
}

// ---------------------------------------------------------------------------
// Fused sparse attention (exact round-1 kernel, proven 323 us / WRITE 16 MB):
// swapped QK^T keeps all 1024 scores of each query register-resident (lane fr
// owns query fr; keys split 256/wave). LDS = bf16 P + ~2KB scratch -> 4
// blocks/CU. DO NOT add register pressure here: the kernel sits at a
// pressure cliff (56 VGPR); the v3 selection rewrite spilled v2[] -> +140 MB
// scratch writes (r3/r5 A/B).
// ---------------------------------------------------------------------------
__global__ __launch_bounds__(256, 4) void attn_k(const u16* __restrict__ qkv,
                                                 const u16* __restrict__ vt,
                                                 u16* __restrict__ aout)
{
  __shared__ u16 sP[16 * 1032];          // P bf16 [query][key], stride 1032
  __shared__ float4 red4[4][16];         // per-wave stats {mx,mn,sm,sq}
  __shared__ uint cntb[2][4][16];        // bisection counts (double-buffered)
  __shared__ uint fcnt[4][16];           // fallback band counts
  __shared__ float esred[4][16];         // exp-sum partials

  const int t = threadIdx.x;
  const int lane = t & 63;
  const int wv = t >> 6;
  const int bid = blockIdx.x;
  const int sw = ((bid & 7) << 10) | (bid >> 3);   // bijective XCD swizzle (8192 = 8*1024)
  const int bh = sw >> 6;
  const int rb = sw & 63;
  const int b = bh >> 4, h = bh & 15;
  const size_t row0 = (size_t)b * 1024;
  const int colQ = h * 64;
  const int fr = lane & 15, q = lane >> 4;

  // Q fragments (B operand of swapped mfma): rows fr = query
  const u16* qrow = qkv + (row0 + rb * 16 + fr) * 3072 + colQ + q * 8;
  const bf16x8 bq0 = *(const bf16x8*)(qrow);
  const bf16x8 bq1 = *(const bf16x8*)(qrow + 32);

  // ---- phase B: swapped scores. Wave wv owns keys [wv*256, wv*256+256).
  // v2[tt][r] = score[key = wv*256 + tt*16 + q*4 + r][query = fr]
  float v2[16][4];
  const u16* kbase = qkv + (row0 + wv * 256 + fr) * 3072 + 1024 + colQ + q * 8;
#pragma unroll
  for (int tt = 0; tt < 16; ++tt) {
    const u16* kp = kbase + (size_t)tt * 16 * 3072;
    const bf16x8 ak0 = *(const bf16x8*)(kp);
    const bf16x8 ak1 = *(const bf16x8*)(kp + 32);
    f32x4 sacc = {};
    sacc = __builtin_amdgcn_mfma_f32_16x16x32_bf16(ak0, bq0, sacc, 0, 0, 0);
    sacc = __builtin_amdgcn_mfma_f32_16x16x32_bf16(ak1, bq1, sacc, 0, 0, 0);
#pragma unroll
    for (int r = 0; r < 4; ++r) v2[tt][r] = sacc[r];
  }

  // ---- phase C: per-query stats (lane's 64 values all belong to query fr)
  float mx = v2[0][0], mn = v2[0][0], sm = 0.f, sq = 0.f;
#pragma unroll
  for (int tt = 0; tt < 16; ++tt)
#pragma unroll
    for (int r = 0; r < 4; ++r) {
      const float x = v2[tt][r];
      mx = fmaxf(mx, x); mn = fminf(mn, x); sm += x; sq += x * x;
    }
  // combine the 4 q-lanes of this query within the wave (lanes fr+16q)
  mx = fmaxf(mx, __shfl_xor(mx, 16)); mx = fmaxf(mx, __shfl_xor(mx, 32));
  mn = fminf(mn, __shfl_xor(mn, 16)); mn = fminf(mn, __shfl_xor(mn, 32));
  sm += __shfl_xor(sm, 16); sm += __shfl_xor(sm, 32);
  sq += __shfl_xor(sq, 16); sq += __shfl_xor(sq, 32);
  if (lane < 16) red4[wv][fr] = make_float4(mx, mn, sm, sq);
  __syncthreads();
  {
    const float4 a0 = red4[0][fr], a1 = red4[1][fr], a2 = red4[2][fr], a3 = red4[3][fr];
    mx = fmaxf(fmaxf(a0.x, a1.x), fmaxf(a2.x, a3.x));
    mn = fminf(fminf(a0.y, a1.y), fminf(a2.y, a3.y));
    sm = a0.z + a1.z + a2.z + a3.z;
    sq = a0.w + a1.w + a2.w + a3.w;
  }

  // ---- top-102 threshold search (same numerics as proven version)
  float lo, hi, tcur, texact = 0.f;
  int nlo = 1024, nhi = 0;
  bool done = false;
  {
    const float mu = sm * (1.0f / 1024.0f);
    const float var = fmaxf(sq * (1.0f / 1024.0f) - mu * mu, 0.0f);
    const float sd = sqrtf(var + 1e-20f);
    lo = mn - fabsf(mn) * 1e-6f - 1e-12f;
    hi = mx + fabsf(mx) * 1e-6f + 1e-12f;
    const float t0 = mu + 1.2816f * sd;            // Gaussian 10% upper-quantile seed
    const float wdt = hi - lo;
    tcur = fminf(fmaxf(t0, lo + 0.02f * wdt), hi - 0.02f * wdt);
  }

  for (int it = 0; it < 10; ++it) {
    if (__ballot(!done) == 0ull) break;            // identical across waves
    int c_ = 0;
#pragma unroll
    for (int tt = 0; tt < 16; ++tt)
#pragma unroll
      for (int r = 0; r < 4; ++r) c_ += (v2[tt][r] >= tcur) ? 1 : 0;
    c_ += __shfl_xor(c_, 16); c_ += __shfl_xor(c_, 32);
    if (lane < 16) cntb[it & 1][wv][fr] = (uint)c_;
    __syncthreads();
    const int cc = (int)(cntb[it & 1][0][fr] + cntb[it & 1][1][fr] +
                         cntb[it & 1][2][fr] + cntb[it & 1][3][fr]);
    if (!done) {
      if (cc == 102) { done = true; texact = tcur; }
      else if (cc > 102) { lo = tcur; nlo = cc; }
      else { hi = tcur; nhi = cc; }
      float tn;
      if (it & 1) tn = 0.5f * (lo + hi);
      else {
        const float den = (float)(nlo - nhi);
        tn = lo + (hi - lo) * ((float)(nlo - 102) / den);
      }
      const float wdt = hi - lo;
      tcur = fminf(fmaxf(tn, lo + 0.02f * wdt), hi - 0.02f * wdt);
    }
  }

  // ---- build keep-mask (64 bits, bit = tt*4+r)
  uint64_t kmask = 0ull;
  const uint64_t anymask = __ballot(!done);        // identical across waves
  if (anymask == 0ull) {
#pragma unroll
    for (int tt = 0; tt < 16; ++tt)
#pragma unroll
      for (int r = 0; r < 4; ++r)
        if (v2[tt][r] >= texact) kmask |= 1ull << (tt * 4 + r);
  } else {
    // rare fallback: keep all >= hi, fill remaining from band [lo,hi) in
    // deterministic (wave, q, tt, r) order via cross-lane prefix sums.
    const float thr = done ? texact : hi;
    int bc = 0;
#pragma unroll
    for (int tt = 0; tt < 16; ++tt)
#pragma unroll
      for (int r = 0; r < 4; ++r) {
        const float x = v2[tt][r];
        if (x >= thr) kmask |= 1ull << (tt * 4 + r);
        bc += (!done && x >= lo && x < hi) ? 1 : 0;
      }
    int bw = bc + __shfl_xor(bc, 16);
    bw += __shfl_xor(bw, 32);
    if (lane < 16) fcnt[wv][fr] = (uint)bw;
    __syncthreads();
    if (!done) {
      int pre = 0;
#pragma unroll
      for (int w = 0; w < 4; ++w) if (w < wv) pre += (int)fcnt[w][fr];
#pragma unroll
      for (int qq = 0; qq < 3; ++qq) {
        const int ov = __shfl(bc, fr + 16 * qq);
        if (qq < q) pre += ov;
      }
      const int need = 102 - nhi;
#pragma unroll
      for (int tt = 0; tt < 16; ++tt)
#pragma unroll
        for (int r = 0; r < 4; ++r) {
          const float x = v2[tt][r];
          if (x >= lo && x < hi) {
            if (pre < need) kmask |= 1ull << (tt * 4 + r);
            ++pre;
          }
        }
    }
  }

  // ---- exp + normalize (overwrite v2 in place), cross-wave denominator
  const float CEXP = 0.125f * 1.44269504f;   // head_dim^-0.5 * log2(e)
  float es = 0.f;
#pragma unroll
  for (int tt = 0; tt < 16; ++tt)
#pragma unroll
    for (int r = 0; r < 4; ++r) {
      const float e = ((kmask >> (tt * 4 + r)) & 1ull) ? exp2f((v2[tt][r] - mx) * CEXP) : 0.0f;
      v2[tt][r] = e;
      es += e;
    }
  es += __shfl_xor(es, 16); es += __shfl_xor(es, 32);
  if (lane < 16) esred[wv][fr] = es;
  __syncthreads();
  const float inv = 1.0f / (esred[0][fr] + esred[1][fr] + esred[2][fr] + esred[3][fr]);

  // ---- write P (bf16, packed pairs along r)
  u16* prow = sP + (size_t)fr * 1032 + wv * 256;
#pragma unroll
  for (int tt = 0; tt < 16; ++tt) {
#pragma unroll
    for (int rp = 0; rp < 2; ++rp) {
      const u16 p0 = f2bf(v2[tt][2 * rp] * inv);
      const u16 p1 = f2bf(v2[tt][2 * rp + 1] * inv);
      *(uint*)(prow + tt * 16 + q * 4 + 2 * rp) = (uint)p0 | ((uint)p1 << 16);
    }
  }
  __syncthreads();

  // ---- phase D: O = P V (P from LDS, V^T fragments direct from global vt)
  const u16* vtb = vt + (((size_t)(b * 16 + h)) * 64 + wv * 16 + fr) * 1024 + q * 8;
  const u16* pbase = sP + fr * 1032 + q * 8;
  f32x4 oacc = {};
#pragma unroll
  for (int c = 0; c < 16; ++c) {
    const bf16x8 ap0 = *(const bf16x8*)(pbase + c * 64);
    const bf16x8 ap1 = *(const bf16x8*)(pbase + c * 64 + 32);
    const bf16x8 bv0 = *(const bf16x8*)(vtb + c * 64);
    const bf16x8 bv1 = *(const bf16x8*)(vtb + c * 64 + 32);
    oacc = __builtin_amdgcn_mfma_f32_16x16x32_bf16(ap0, bv0, oacc, 0, 0, 0);
    oacc = __builtin_amdgcn_mfma_f32_16x16x32_bf16(ap1, bv1, oacc, 0, 0, 0);
  }
#pragma unroll
  for (int r = 0; r < 4; ++r)
    aout[(row0 + rb * 16 + q * 4 + r) * 1024 + colQ + wv * 16 + fr] = f2bf(oacc[r]);
}

// ---------------------------------------------------------------------------
extern "C" void kernel_launch(void* const* d_in, const int* in_sizes, int n_in,
                              void* d_out, int out_size, void* d_ws, size_t ws_size,
                              hipStream_t stream)
{
  (void)in_sizes; (void)n_in; (void)out_size; (void)ws_size;
  const void* x     = d_in[0];
  const void* ln1w  = d_in[1];
  const void* ln1b  = d_in[2];
  const void* qkvw  = d_in[3];
  const void* qkvb  = d_in[4];
  const void* outw  = d_in[5];
  const void* outb  = d_in[6];
  const void* ln2w  = d_in[7];
  const void* ln2b  = d_in[8];
  const void* w1    = d_in[9];
  const void* b1    = d_in[10];
  const void* w2    = d_in[11];
  const void* b2    = d_in[12];
  const void* mask1 = d_in[13];
  const void* mask2 = d_in[14];

  char* ws = (char*)d_ws;
  const size_t MB = 1ull << 20;
  u16*   xn1    = (u16*)(ws);                 // [0,16) MiB; reused as attn_o
  u16*   qkv    = (u16*)(ws + 16 * MB);       // [16,64) MiB
  u16*   xn2    = qkv;                        // [16,32) after attn
  u16*   w1c    = (u16*)(ws + 32 * MB);       // [32,40)
  u16*   w2c    = (u16*)(ws + 40 * MB);       // [40,48)
  float* x2     = (float*)(ws + 64 * MB);     // [64,96) fp32 residual
  u16*   h1     = (u16*)(ws + 96 * MB);       // [96,160); head reused for wq/wo/vt first
  u16*   wq     = (u16*)(ws + 96 * MB);       // [96,102)
  u16*   wo     = (u16*)(ws + 102 * MB);      // [102,104)
  u16*   vt     = (u16*)(ws + 104 * MB);      // [104,120) V^T, dead before FFN1
  int*   flagp  = (int*)(ws + 160 * MB);
  u16*   attn_o = xn1;

  sniff_k<<<1, 256, 0, stream>>>((const u16*)x, flagp);
  cvt_k<<<3072, 256, 0, stream>>>(qkvw, wq, flagp, 3072 * 1024);
  cvt_k<<<1024, 256, 0, stream>>>(outw, wo, flagp, 1024 * 1024);

  ln_k<false><<<8192, 256, 0, stream>>>(x, ln1w, ln1b, xn1, flagp);
  gemm_bt<0><<<dim3(24, 64), 256, 0, stream>>>(xn1, wq, qkvb, nullptr, nullptr, qkv, 8192, 3072, 1024, flagp);
  vtrans_k<<<2048, 256, 0, stream>>>(qkv, vt);
  attn_k<<<8192, 256, 0, stream>>>(qkv, vt, attn_o);
  gemm_bt<1><<<dim3(8, 64), 256, 0, stream>>>(attn_o, wo, outb, x, nullptr, x2, 8192, 1024, 1024, flagp);

  cvt_k<<<4096, 256, 0, stream>>>(w1, w1c, flagp, 4096 * 1024);
  cvt_k<<<4096, 256, 0, stream>>>(w2, w2c, flagp, 4096 * 1024);

  ln_k<true><<<8192, 256, 0, stream>>>(x2, ln2w, ln2b, xn2, flagp);
  gemm_bt<2><<<dim3(32, 64), 256, 0, stream>>>(xn2, w1c, b1, mask1, nullptr, h1, 8192, 4096, 1024, flagp);
  gemm_bt<3><<<dim3(8, 64), 256, 0, stream>>>(h1, w2c, b2, mask2, x2, d_out, 8192, 1024, 4096, flagp);
}